// Round 1
// baseline (251.419 us; speedup 1.0000x reference)
//
#include <hip/hip_runtime.h>
#include <math.h>

#define NSPECIES 7
#define NRBF 16
#define NPAIRS_SP 28   // 7*8/2
#define SUBLEN 32      // 8*4
#define ROWLEN 1008    // NSPECIES*NRBF + NPAIRS_SP*SUBLEN = 112 + 896
#define ANG_OFF 112

// SHFR step = (0.51-0.08)/16 = 0.026875 ; SHFA step = (0.35-0.08)/8 = 0.03375
// SHFZ[z] = pi/8 + z*pi/4 -> cos/sin constants below.

__global__ void radial_kernel(const float* __restrict__ d_ij,
                              const int* __restrict__ pair_indices,
                              const int* __restrict__ species,
                              float* __restrict__ out,
                              int P) {
    int tid = blockIdx.x * blockDim.x + threadIdx.x;
    int p = tid >> 4;          // pair index
    int k = tid & 15;          // RBF bin
    if (p >= P) return;

    float d = d_ij[p];
    int i = pair_indices[p];
    int j = pair_indices[P + p];
    int si = species[i];
    int sj = species[j];

    // cutoff(d, RCR): all d < RCR by construction, keep guard for exactness
    float fc = (d <= 0.51f) ? 0.5f * (cosf(d * (float)(M_PI / 0.51)) + 1.0f) : 0.0f;
    float shfr = 0.08f + (float)k * 0.026875f;
    float diff = d - shfr;
    float rfv = 0.25f * expf(-1970.0f * diff * diff) * fc;

    atomicAdd(out + (size_t)i * ROWLEN + sj * NRBF + k, rfv);
    atomicAdd(out + (size_t)j * ROWLEN + si * NRBF + k, rfv);
}

__global__ void angular_kernel(const float* __restrict__ r_ij,
                               const int* __restrict__ pair_indices,
                               const int* __restrict__ species,
                               const int* __restrict__ close_idx,
                               const int* __restrict__ central_atom_index,
                               const int* __restrict__ pair_index12,
                               const int* __restrict__ sign12,
                               float* __restrict__ out,
                               int P, int T) {
    int tid = blockIdx.x * blockDim.x + threadIdx.x;
    int t = tid >> 5;          // triple index
    int lane = tid & 31;       // a*4+z within SUBLEN
    if (t >= T) return;

    int p1 = pair_index12[t];
    int p2 = pair_index12[T + t];
    int s1 = sign12[t];
    int s2 = sign12[T + t];
    int ca = central_atom_index[t];

    int gp1 = close_idx[p1];   // global pair index
    int gp2 = close_idx[p2];

    float sg1 = (float)s1, sg2 = (float)s2;
    float v1x = r_ij[gp1 * 3 + 0] * sg1;
    float v1y = r_ij[gp1 * 3 + 1] * sg1;
    float v1z = r_ij[gp1 * 3 + 2] * sg1;
    float v2x = r_ij[gp2 * 3 + 0] * sg2;
    float v2y = r_ij[gp2 * 3 + 1] * sg2;
    float v2z = r_ij[gp2 * 3 + 2] * sg2;

    // species of the non-central atom of each pair
    int spa = species[pair_indices[(s1 == 1 ? P : 0) + gp1]];
    int spb = species[pair_indices[(s2 == 1 ? P : 0) + gp2]];

    float d1 = sqrtf(v1x * v1x + v1y * v1y + v1z * v1z);
    float d2 = sqrtf(v2x * v2x + v2y * v2y + v2z * v2z);
    float dot = v1x * v2x + v1y * v2y + v1z * v2z;

    float cosang = 0.95f * dot / (d1 * d2);
    float sinang = sqrtf(fmaxf(1.0f - cosang * cosang, 0.0f));  // ang in [0,pi]

    float fc1 = (d1 <= 0.35f) ? 0.5f * (cosf(d1 * (float)(M_PI / 0.35)) + 1.0f) : 0.0f;
    float fc2 = (d2 <= 0.35f) ? 0.5f * (cosf(d2 * (float)(M_PI / 0.35)) + 1.0f) : 0.0f;
    float fcj = fc1 * fc2;

    int a = lane >> 2;
    int z = lane & 3;

    float shfa = 0.08f + (float)a * 0.03375f;
    float dm = (d1 + d2) * 0.5f - shfa;
    float f2 = expf(-800.0f * dm * dm);

    // cos(ang - SHFZ[z]) = cosang*cos(SHFZ) + sinang*sin(SHFZ)
    // SHFZ = pi/8 + z*pi/4: cos = {c8, s8, -s8, -c8}, sin = {s8, c8, c8, s8}
    const float c8 = 0.92387953251f;   // cos(pi/8)
    const float s8 = 0.38268343236f;   // sin(pi/8)
    bool mid = (z == 1) | (z == 2);
    float cmag = mid ? s8 : c8;
    float smag = mid ? c8 : s8;
    float cz = (z >= 2) ? -cmag : cmag;

    float base = 0.5f * (1.0f + cosang * cz + sinang * smag);
    // base^32 via 5 squarings (even power: safe for tiny-negative fp error)
    float x = base * base;  // ^2
    x = x * x;              // ^4
    x = x * x;              // ^8
    x = x * x;              // ^16
    x = x * x;              // ^32

    float term = 2.0f * f2 * x * fcj;

    int lo = min(spa, spb), hi = max(spa, spb);
    int triu = lo * NSPECIES - (lo * (lo - 1)) / 2 + (hi - lo);

    atomicAdd(out + (size_t)ca * ROWLEN + ANG_OFF + triu * SUBLEN + lane, term);
}

extern "C" void kernel_launch(void* const* d_in, const int* in_sizes, int n_in,
                              void* d_out, int out_size, void* d_ws, size_t ws_size,
                              hipStream_t stream) {
    const float* d_ij               = (const float*)d_in[0];
    const float* r_ij               = (const float*)d_in[1];
    const int*   pair_indices       = (const int*)d_in[2];
    const int*   species            = (const int*)d_in[3];
    const int*   close_idx          = (const int*)d_in[4];
    const int*   central_atom_index = (const int*)d_in[5];
    const int*   pair_index12       = (const int*)d_in[6];
    const int*   sign12             = (const int*)d_in[7];
    float* out = (float*)d_out;

    int P = in_sizes[0];      // number of pairs (d_ij is (P,1))
    int T = in_sizes[5];      // number of angular triples

    hipMemsetAsync(d_out, 0, (size_t)out_size * sizeof(float), stream);

    {
        long long threads = (long long)P * 16;
        int blocks = (int)((threads + 255) / 256);
        radial_kernel<<<blocks, 256, 0, stream>>>(d_ij, pair_indices, species, out, P);
    }
    {
        long long threads = (long long)T * 32;
        int blocks = (int)((threads + 255) / 256);
        angular_kernel<<<blocks, 256, 0, stream>>>(r_ij, pair_indices, species, close_idx,
                                                   central_atom_index, pair_index12, sign12,
                                                   out, P, T);
    }
}